// Round 5
// baseline (251.958 us; speedup 1.0000x reference)
//
#include <hip/hip_runtime.h>
#include <hip/hip_bf16.h>
#include <math.h>

#define D 384
#define EPS 1e-8f

#define ROWS_PER_BLOCK 256   // 4 waves x 64 rows
#define COLS_PER_SPLIT 1024
#define POS_W 128            // cols per position (epilogue granularity)
#define BKC 64               // k elements per LDS stage
#define NSTAGE 6             // 384/64
#define NPOS 8               // 1024/128
#define NST_TOT (NPOS * NSTAGE)
#define LDSROW 144           // 128 data bytes + 16 pad (breaks bank aliasing)

typedef __bf16  bf16x8  __attribute__((ext_vector_type(8)));
typedef float   floatx4 __attribute__((ext_vector_type(4)));

// ---------------- kernel 1: rnorm + normalized bf16 cast ----------------
__global__ __launch_bounds__(256) void prep_kernel(const float* __restrict__ in,
                                                   float* __restrict__ rnorm,
                                                   __hip_bfloat16* __restrict__ xb, int N) {
    int row = blockIdx.x * 4 + (threadIdx.x >> 6);   // one wave per row
    if (row >= N) return;
    int lane = threadIdx.x & 63;
    const float* p = in + (size_t)row * D;
    float v[6];
    float s = 0.f;
#pragma unroll
    for (int c = 0; c < 6; ++c) { v[c] = p[lane + 64 * c]; s += v[c] * v[c]; }
#pragma unroll
    for (int off = 32; off >= 1; off >>= 1) s += __shfl_xor(s, off, 64);
    float rn = 1.0f / fmaxf(sqrtf(s), EPS);
    if (lane == 0) rnorm[row] = rn;
    __hip_bfloat16* q = xb + (size_t)row * D;
#pragma unroll
    for (int c = 0; c < 6; ++c) q[lane + 64 * c] = __float2bfloat16(v[c] * rn);
}

// ---------------- kernel 2: row-ownership MFMA scan with running argmax ----------------
// Each block owns 256 rows, scans 1024 cols (8 positions of 128).
// A fragments live in VGPRs for the whole kernel; B is double-buffered in LDS.
// Argmax folds into per-lane running (val, col) registers: ~3 ops/candidate,
// no shuffles/atomics until the very end.
__global__ __launch_bounds__(256, 1) void maxdot_rows(const __hip_bfloat16* __restrict__ xb,
                                                      unsigned long long* __restrict__ best) {
    __shared__ char Bs[2 * POS_W * LDSROW];          // 2 x 18 KB

    const int t    = threadIdx.x;
    const int lane = t & 63;
    const int wv   = t >> 6;
    const int quad = lane >> 4, l16 = lane & 15;
    const int rb   = blockIdx.x >> 3;                // 32 row-blocks
    const int cs   = blockIdx.x & 7;                 // 8 col-splits
    const int row0b = rb * ROWS_PER_BLOCK;
    const int col0s = cs * COLS_PER_SPLIT;
    const int wrow0 = row0b + wv * 64;

    // ---- A preload into registers: 4 mi-tiles x 12 k32-steps x 16 B ----
    bf16x8 A[4][12];
#pragma unroll
    for (int mi = 0; mi < 4; ++mi) {
        const __hip_bfloat16* pr = xb + (size_t)(wrow0 + mi * 16 + l16) * D + quad * 8;
#pragma unroll
        for (int s = 0; s < 12; ++s)
            A[mi][s] = *(const bf16x8*)(pr + s * 32);
    }

    floatx4 acc[4][8];
#pragma unroll
    for (int mi = 0; mi < 4; ++mi)
#pragma unroll
        for (int ni = 0; ni < 8; ++ni) acc[mi][ni] = (floatx4){0.f, 0.f, 0.f, 0.f};

    float rv[16];
    int   ri[16];
#pragma unroll
    for (int i = 0; i < 16; ++i) { rv[i] = -3.0f; ri[i] = 0; }

    const int c_st = t >> 3;          // staging: col within position
    const int g_st = t & 7;           // 16-B granule within 128-B k-row

    // prefetch stage 0 into regs
    uint4 sv[4];
    {
        const int colbase = col0s;    // pos 0, kb 0
#pragma unroll
        for (int i = 0; i < 4; ++i)
            sv[i] = *(const uint4*)(xb + (size_t)(colbase + c_st + i * 32) * D + g_st * 8);
    }

    int buf = 0;
    for (int st = 0; st < NST_TOT; ++st) {
        char* bbase = Bs + buf * (POS_W * LDSROW);
        // commit staged regs to LDS (padded rows -> conflict-free reads)
#pragma unroll
        for (int i = 0; i < 4; ++i)
            *(uint4*)(bbase + (c_st + i * 32) * LDSROW + g_st * 16) = sv[i];
        __syncthreads();

        // issue next stage's global loads (overlap with compute below)
        if (st + 1 < NST_TOT) {
            int stn = st + 1;
            int posn = stn / NSTAGE, kbn = stn % NSTAGE;
            const __hip_bfloat16* src = xb + (size_t)(col0s + posn * POS_W + c_st) * D
                                           + kbn * BKC + g_st * 8;
#pragma unroll
            for (int i = 0; i < 4; ++i)
                sv[i] = *(const uint4*)(src + (size_t)i * 32 * D);
        }

        const int kb = st % NSTAGE;
#pragma unroll
        for (int kk = 0; kk < 2; ++kk) {             // two k32 MFMA steps per stage
            const int gk = kb * 2 + kk;              // global k32 index 0..11
            bf16x8 bfr[8];
#pragma unroll
            for (int ni = 0; ni < 8; ++ni)
                bfr[ni] = *(const bf16x8*)(bbase + (ni * 16 + l16) * LDSROW + kk * 64 + quad * 16);
#pragma unroll
            for (int mi = 0; mi < 4; ++mi)
#pragma unroll
                for (int ni = 0; ni < 8; ++ni)
                    acc[mi][ni] = __builtin_amdgcn_mfma_f32_16x16x32_bf16(A[mi][gk], bfr[ni], acc[mi][ni], 0, 0, 0);
        }

        if (kb == NSTAGE - 1) {                      // position finished: fold into running
            const int pos = st / NSTAGE;
            const int colbase = col0s + pos * POS_W;
            const bool dg = (colbase < row0b + ROWS_PER_BLOCK) && (row0b < colbase + POS_W);
#pragma unroll
            for (int mi = 0; mi < 4; ++mi)
#pragma unroll
                for (int reg = 0; reg < 4; ++reg) {
                    const int r = wrow0 + mi * 16 + quad * 4 + reg;
                    float d[8];
#pragma unroll
                    for (int ni = 0; ni < 8; ++ni) d[ni] = acc[mi][ni][reg];
                    if (dg) {
#pragma unroll
                        for (int ni = 0; ni < 8; ++ni)
                            if (colbase + ni * 16 + l16 == r) d[ni] = -2.0f;
                    }
                    float m = d[0]; int ci = 0;
#pragma unroll
                    for (int ni = 1; ni < 8; ++ni) { // ties -> lower ni (first occurrence)
                        bool gt = d[ni] > m;
                        m  = gt ? d[ni] : m;
                        ci = gt ? ni : ci;
                    }
                    const int slot = mi * 4 + reg;
                    bool upd = m > rv[slot];         // ties -> earlier position
                    rv[slot] = upd ? m : rv[slot];
                    ri[slot] = upd ? (colbase + ci * 16 + l16) : ri[slot];
#pragma unroll
                    for (int ni = 0; ni < 8; ++ni) acc[mi][ni][reg] = 0.f;
                }
        }
        buf ^= 1;
    }

    // ---- final cross-lane reduce over the 16 cols-lanes, then one atomic/row ----
#pragma unroll
    for (int slot = 0; slot < 16; ++slot) {
        float v = rv[slot]; int ci = ri[slot];
#pragma unroll
        for (int m = 1; m < 16; m <<= 1) {
            float ov = __shfl_xor(v, m, 64);
            int   oi = __shfl_xor(ci, m, 64);
            bool take = (ov > v) || (ov == v && oi < ci);
            v  = take ? ov : v;
            ci = take ? oi : ci;
        }
        if (l16 == 0) {
            const int r = wrow0 + (slot >> 2) * 16 + quad * 4 + (slot & 3);
            unsigned u = __float_as_uint(v);
            u = (u & 0x80000000u) ? ~u : (u | 0x80000000u);
            unsigned long long key = ((unsigned long long)u << 32) | (unsigned)(~ci);
            atomicMax(best + r, key);
        }
    }
}

// ---------------- kernel 3: exact fp32 distance + loss ----------------
__global__ __launch_bounds__(256) void loss_kernel(const float* __restrict__ in,
                                                   const float* __restrict__ rnorm,
                                                   const unsigned long long* __restrict__ best,
                                                   float* __restrict__ out, int N) {
    __shared__ float part[4];
    const int wave = threadIdx.x >> 6, lane = threadIdx.x & 63;
    const int gw = blockIdx.x * 4 + wave;            // 1024 waves total
    float local = 0.f;
    for (int row = gw; row < N; row += 1024) {
        unsigned long long key = best[row];
        int j = (int)(~(unsigned)(key & 0xffffffffull));
        float rni = rnorm[row], rnj = rnorm[j];
        const float* pi = in + (size_t)row * D;
        const float* pj = in + (size_t)j * D;
        float s = 0.f;
#pragma unroll
        for (int c = 0; c < 6; ++c) {
            float xi = pi[lane + 64 * c] * rni;
            float xj = pj[lane + 64 * c] * rnj;
            float dvv = xi - xj + EPS;               // ||x - nn_x + eps||
            s += dvv * dvv;
        }
#pragma unroll
        for (int off = 32; off > 0; off >>= 1) s += __shfl_down(s, off, 64);
        if (lane == 0) local += -logf(sqrtf(s) + EPS);
    }
    if (lane == 0) part[wave] = local;
    __syncthreads();
    if (threadIdx.x == 0)
        atomicAdd(out, (part[0] + part[1] + part[2] + part[3]) / (float)N);
}

extern "C" void kernel_launch(void* const* d_in, const int* in_sizes, int n_in,
                              void* d_out, int out_size, void* d_ws, size_t ws_size,
                              hipStream_t stream) {
    const float* in = (const float*)d_in[0];
    float* out = (float*)d_out;
    const int N = in_sizes[0] / D;                   // 8192

    // workspace layout: rnorm (N f32) | best (N u64) | xb (N*D bf16)
    char* ws = (char*)d_ws;
    float* rnorm = (float*)ws;
    unsigned long long* best = (unsigned long long*)(ws + 64 * 1024);
    __hip_bfloat16* xb = (__hip_bfloat16*)(ws + 192 * 1024);

    (void)hipMemsetAsync(best, 0, (size_t)N * 8, stream);  // ws re-poisoned each call
    (void)hipMemsetAsync(out, 0, sizeof(float), stream);

    prep_kernel<<<N / 4, 256, 0, stream>>>(in, rnorm, xb, N);
    maxdot_rows<<<256, 256, 0, stream>>>(xb, best);        // 32 row-blocks x 8 col-splits
    loss_kernel<<<256, 256, 0, stream>>>(in, rnorm, best, out, N);
}

// Round 6
// 144.883 us; speedup vs baseline: 1.7390x; 1.7390x over previous
//
#include <hip/hip_runtime.h>
#include <hip/hip_bf16.h>
#include <math.h>

#define D 384
#define EPS 1e-8f

#define RPB 256            // rows per block (4 waves x 64)
#define CPS 512            // cols per split
#define POS_W 128          // cols per position (fold granularity)
#define NPOS 4             // 512/128
#define NKB 12             // 384/32 k-steps

typedef __bf16  bf16x8  __attribute__((ext_vector_type(8)));
typedef float   floatx4 __attribute__((ext_vector_type(4)));

// ---------------- kernel 1: rnorm + normalized bf16 cast ----------------
__global__ __launch_bounds__(256) void prep_kernel(const float* __restrict__ in,
                                                   float* __restrict__ rnorm,
                                                   __hip_bfloat16* __restrict__ xb, int N) {
    int row = blockIdx.x * 4 + (threadIdx.x >> 6);   // one wave per row
    if (row >= N) return;
    int lane = threadIdx.x & 63;
    const float* p = in + (size_t)row * D;
    float v[6];
    float s = 0.f;
#pragma unroll
    for (int c = 0; c < 6; ++c) { v[c] = p[lane + 64 * c]; s += v[c] * v[c]; }
#pragma unroll
    for (int off = 32; off >= 1; off >>= 1) s += __shfl_xor(s, off, 64);
    float rn = 1.0f / fmaxf(sqrtf(s), EPS);
    if (lane == 0) rnorm[row] = rn;
    __hip_bfloat16* q = xb + (size_t)row * D;
#pragma unroll
    for (int c = 0; c < 6; ++c) q[lane + 64 * c] = __float2bfloat16(v[c] * rn);
}

// ---------------- kernel 2: row-ownership MFMA scan, A direct-from-global ----------------
// Block owns 256 rows, scans 512 cols (4 positions of 128). B goes through an
// 8 KB LDS stage (global_load_lds, 64 B/col -> 2-way-free banks); A fragments
// load straight global->VGPR per k-step (xb is L2/L3-hot), removing A from the
// LDS pipe entirely. Argmax folds into per-lane running (val,col) regs: 3 ops
// per candidate, no shuffles/atomics until the end.
__global__ __launch_bounds__(256, 2) void maxdot_rows(const __hip_bfloat16* __restrict__ xb,
                                                      unsigned long long* __restrict__ best) {
    __shared__ char Bs[POS_W * 64];                  // 8 KB: 128 cols x 64 B (32 k)

    const int t    = threadIdx.x;
    const int lane = t & 63;
    const int wv   = t >> 6;
    const int quad = lane >> 4, l16 = lane & 15;
    const int rb   = blockIdx.x >> 4;                // 32 row-blocks
    const int cs   = blockIdx.x & 15;                // 16 col-splits
    const int row0b = rb * RPB;
    const int col0s = cs * CPS;
    const int wrow0 = row0b + wv * 64;

    floatx4 acc[4][8];
#pragma unroll
    for (int mi = 0; mi < 4; ++mi)
#pragma unroll
        for (int ni = 0; ni < 8; ++ni) acc[mi][ni] = (floatx4){0.f, 0.f, 0.f, 0.f};

    float rv[16];
    int   ri[16];
#pragma unroll
    for (int i = 0; i < 16; ++i) { rv[i] = -3.0f; ri[i] = 0; }

    // B staging indices: p = t (+256): col = p>>2, 16-B granule = p&3
    const int sc0 = t >> 2,       sg0 = t & 3;
    const int sc1 = (t + 256) >> 2, sg1 = (t + 256) & 3;

    for (int pos = 0; pos < NPOS; ++pos) {
        const int colbase = col0s + pos * POS_W;

        for (int kb = 0; kb < NKB; ++kb) {
            __syncthreads();                         // prior frag reads done
            {   // stage B: 128 cols x 64 B via 2 glds/thread (LDS = load order)
                const char* g0 = (const char*)(xb + (size_t)(colbase + sc0) * D + kb * 32) + sg0 * 16;
                const char* g1 = (const char*)(xb + (size_t)(colbase + sc1) * D + kb * 32) + sg1 * 16;
                __builtin_amdgcn_global_load_lds((const __attribute__((address_space(1))) void*)g0,
                                                 (__attribute__((address_space(3))) void*)(Bs + t * 16), 16, 0, 0);
                __builtin_amdgcn_global_load_lds((const __attribute__((address_space(1))) void*)g1,
                                                 (__attribute__((address_space(3))) void*)(Bs + (t + 256) * 16), 16, 0, 0);
            }
            // A fragments straight from global (latency hidden by the barrier)
            bf16x8 af[4];
#pragma unroll
            for (int mi = 0; mi < 4; ++mi)
                af[mi] = *(const bf16x8*)(xb + (size_t)(wrow0 + mi * 16 + l16) * D + kb * 32 + quad * 8);
            __syncthreads();                         // B staged (vmcnt drained)

            bf16x8 bfr[8];
#pragma unroll
            for (int ni = 0; ni < 8; ++ni)
                bfr[ni] = *(const bf16x8*)(Bs + (ni * 16 + l16) * 64 + quad * 16);
#pragma unroll
            for (int mi = 0; mi < 4; ++mi)
#pragma unroll
                for (int ni = 0; ni < 8; ++ni)
                    acc[mi][ni] = __builtin_amdgcn_mfma_f32_16x16x32_bf16(af[mi], bfr[ni], acc[mi][ni], 0, 0, 0);
        }

        // ---- fold position into running (val, col); then zero acc ----
        const bool dg = (colbase < row0b + RPB) && (row0b < colbase + POS_W);
#pragma unroll
        for (int mi = 0; mi < 4; ++mi)
#pragma unroll
            for (int reg = 0; reg < 4; ++reg) {
                const int r = wrow0 + mi * 16 + quad * 4 + reg;
                float d[8];
#pragma unroll
                for (int ni = 0; ni < 8; ++ni) d[ni] = acc[mi][ni][reg];
                if (dg) {
#pragma unroll
                    for (int ni = 0; ni < 8; ++ni)
                        if (colbase + ni * 16 + l16 == r) d[ni] = -2.0f;
                }
                float m = d[0]; int ci = 0;
#pragma unroll
                for (int ni = 1; ni < 8; ++ni) {     // ties -> lower ni (lower col)
                    bool gt = d[ni] > m;
                    m  = gt ? d[ni] : m;
                    ci = gt ? ni : ci;
                }
                const int slot = mi * 4 + reg;
                bool upd = m > rv[slot];             // ties -> earlier position (lower col)
                rv[slot] = upd ? m : rv[slot];
                ri[slot] = upd ? (colbase + ci * 16 + l16) : ri[slot];
#pragma unroll
                for (int ni = 0; ni < 8; ++ni) acc[mi][ni][reg] = 0.f;
            }
    }

    // ---- final cross-lane reduce over the 16 col-lanes, one atomic per row ----
#pragma unroll
    for (int slot = 0; slot < 16; ++slot) {
        float v = rv[slot]; int ci = ri[slot];
#pragma unroll
        for (int m = 1; m < 16; m <<= 1) {
            float ov = __shfl_xor(v, m, 64);
            int   oi = __shfl_xor(ci, m, 64);
            bool take = (ov > v) || (ov == v && oi < ci);
            v  = take ? ov : v;
            ci = take ? oi : ci;
        }
        if (l16 == 0) {
            const int r = wrow0 + (slot >> 2) * 16 + quad * 4 + (slot & 3);
            unsigned u = __float_as_uint(v);
            u = (u & 0x80000000u) ? ~u : (u | 0x80000000u);
            unsigned long long key = ((unsigned long long)u << 32) | (unsigned)(~ci);
            atomicMax(best + r, key);
        }
    }
}

// ---------------- kernel 3: exact fp32 distance + loss ----------------
__global__ __launch_bounds__(256) void loss_kernel(const float* __restrict__ in,
                                                   const float* __restrict__ rnorm,
                                                   const unsigned long long* __restrict__ best,
                                                   float* __restrict__ out, int N) {
    __shared__ float part[4];
    const int wave = threadIdx.x >> 6, lane = threadIdx.x & 63;
    const int gw = blockIdx.x * 4 + wave;            // 1024 waves total
    float local = 0.f;
    for (int row = gw; row < N; row += 1024) {
        unsigned long long key = best[row];
        int j = (int)(~(unsigned)(key & 0xffffffffull));
        float rni = rnorm[row], rnj = rnorm[j];
        const float* pi = in + (size_t)row * D;
        const float* pj = in + (size_t)j * D;
        float s = 0.f;
#pragma unroll
        for (int c = 0; c < 6; ++c) {
            float xi = pi[lane + 64 * c] * rni;
            float xj = pj[lane + 64 * c] * rnj;
            float dvv = xi - xj + EPS;               // ||x - nn_x + eps||
            s += dvv * dvv;
        }
#pragma unroll
        for (int off = 32; off > 0; off >>= 1) s += __shfl_down(s, off, 64);
        if (lane == 0) local += -logf(sqrtf(s) + EPS);
    }
    if (lane == 0) part[wave] = local;
    __syncthreads();
    if (threadIdx.x == 0)
        atomicAdd(out, (part[0] + part[1] + part[2] + part[3]) / (float)N);
}

extern "C" void kernel_launch(void* const* d_in, const int* in_sizes, int n_in,
                              void* d_out, int out_size, void* d_ws, size_t ws_size,
                              hipStream_t stream) {
    const float* in = (const float*)d_in[0];
    float* out = (float*)d_out;
    const int N = in_sizes[0] / D;                   // 8192

    // workspace layout: rnorm (N f32) | best (N u64) | xb (N*D bf16)
    char* ws = (char*)d_ws;
    float* rnorm = (float*)ws;
    unsigned long long* best = (unsigned long long*)(ws + 64 * 1024);
    __hip_bfloat16* xb = (__hip_bfloat16*)(ws + 192 * 1024);

    (void)hipMemsetAsync(best, 0, (size_t)N * 8, stream);  // ws re-poisoned each call
    (void)hipMemsetAsync(out, 0, sizeof(float), stream);

    prep_kernel<<<N / 4, 256, 0, stream>>>(in, rnorm, xb, N);
    maxdot_rows<<<512, 256, 0, stream>>>(xb, best);        // 32 row-blocks x 16 col-splits
    loss_kernel<<<256, 256, 0, stream>>>(in, rnorm, best, out, N);
}